// Round 1
// baseline (215.079 us; speedup 1.0000x reference)
//
#include <hip/hip_runtime.h>

// Problem constants (fixed by reference setup_inputs)
constexpr int B_ = 8;
constexpr int N_ = 16;
constexpr int H_ = 368;
constexpr int W_ = 640;
constexpr int P_ = H_ * W_;          // 235520 pixels per image
constexpr int C_ = 12;               // instance ids 1..12
constexpr float MARGIN_VAR_ = 0.5f;
constexpr float MARGIN_DIST_ = 3.0f;

// Workspace layout (floats)
constexpr int OFF_SUMS = 0;                      // [B][C][N] feature sums
constexpr int OFF_CNT  = OFF_SUMS + B_*C_*N_;    // [B][C]    pixel counts
constexpr int OFF_CEN  = OFF_CNT  + B_*C_;       // [B][C][N] centers
constexpr int OFF_W    = OFF_CEN  + B_*C_*N_;    // [B][C]    pull weights
constexpr int WS_FLOATS = OFF_W + B_*C_;

constexpr int BPI = 128;   // blocks per image
constexpr int TPB = 256;   // threads per block

// ---------------------------------------------------------------------------
// Kernel 1: per-class feature sums + counts (segmented reduction over pixels)
// ---------------------------------------------------------------------------
__global__ __launch_bounds__(TPB) void k_accum(const float* __restrict__ feat,
                                               const int* __restrict__ gt,
                                               float* __restrict__ ws) {
    // Sub-banked LDS accumulators: [class][sub][17] (padded to spread banks)
    __shared__ float lsum[C_][4][17];
    __shared__ float lcnt[C_][4];

    for (int i = threadIdx.x; i < C_*4*17; i += TPB) (&lsum[0][0][0])[i] = 0.f;
    for (int i = threadIdx.x; i < C_*4;    i += TPB) (&lcnt[0][0])[i]    = 0.f;
    __syncthreads();

    const int b   = blockIdx.x / BPI;
    const int blk = blockIdx.x % BPI;
    const float* __restrict__ fb = feat + (size_t)b * N_ * P_;
    const int*   __restrict__ gb = gt   + (size_t)b * P_;
    const int sub = (threadIdx.x >> 4) & 3;  // 4 sub-banks per wave (16 lanes each)

    for (int p = blk * TPB + threadIdx.x; p < P_; p += BPI * TPB) {
        const int lab = gb[p];
        if (lab >= 1 && lab <= C_) {
            const int c = lab - 1;
            atomicAdd(&lcnt[c][sub], 1.0f);
            #pragma unroll
            for (int n = 0; n < N_; ++n) {
                const float v = fb[(size_t)n * P_ + p];
                atomicAdd(&lsum[c][sub][n], v);
            }
        }
    }
    __syncthreads();

    // Flush block partials to global workspace
    for (int i = threadIdx.x; i < C_*N_; i += TPB) {
        const int c = i / N_, n = i % N_;
        const float s = lsum[c][0][n] + lsum[c][1][n] + lsum[c][2][n] + lsum[c][3][n];
        atomicAdd(&ws[OFF_SUMS + ((size_t)b * C_ + c) * N_ + n], s);
    }
    for (int i = threadIdx.x; i < C_; i += TPB) {
        const float s = lcnt[i][0] + lcnt[i][1] + lcnt[i][2] + lcnt[i][3];
        atomicAdd(&ws[OFF_CNT + b * C_ + i], s);
    }
}

// ---------------------------------------------------------------------------
// Kernel 2 (1 block): centers, n_inst, pull weights, push loss -> out[0]
// ---------------------------------------------------------------------------
__global__ __launch_bounds__(TPB) void k_centers_push(float* __restrict__ ws,
                                                      float* __restrict__ out) {
    __shared__ float red[TPB];
    __shared__ float s_ninst;
    const int tid = threadIdx.x;

    // n_inst = number of present (b,c)
    float pres = 0.f;
    if (tid < B_*C_) pres = (ws[OFF_CNT + tid] > 0.f) ? 1.f : 0.f;
    red[tid] = pres;
    __syncthreads();
    for (int s = TPB/2; s > 0; s >>= 1) {
        if (tid < s) red[tid] += red[tid + s];
        __syncthreads();
    }
    if (tid == 0) s_ninst = red[0];
    __syncthreads();
    const float n_inst = s_ninst;

    // centers = sums / max(count,1)
    for (int i = tid; i < B_*C_*N_; i += TPB) {
        const int bc = i / N_;
        const float cnt = ws[OFF_CNT + bc];
        ws[OFF_CEN + i] = ws[OFF_SUMS + i] / fmaxf(cnt, 1.f);
    }
    // pull weight per (b,c): present ? 1/(count * n_inst) : 0
    for (int i = tid; i < B_*C_; i += TPB) {
        const float cnt = ws[OFF_CNT + i];
        ws[OFF_W + i] = (cnt > 0.f && n_inst > 0.f)
                        ? 1.0f / (fmaxf(cnt, 1.f) * fmaxf(n_inst, 1.f)) : 0.f;
    }
    __syncthreads();

    // push: ordered pairs i != j, both present
    float psum = 0.f, pcnt = 0.f;
    for (int idx = tid; idx < B_*C_*C_; idx += TPB) {
        const int b   = idx / (C_*C_);
        const int rem = idx % (C_*C_);
        const int i = rem / C_, j = rem % C_;
        if (i == j) continue;
        const float ci = ws[OFF_CNT + b*C_ + i];
        const float cj = ws[OFF_CNT + b*C_ + j];
        if (ci > 0.f && cj > 0.f) {
            float sq = 0.f;
            #pragma unroll
            for (int n = 0; n < N_; ++n) {
                const float d = ws[OFF_CEN + (b*C_ + i)*N_ + n]
                              - ws[OFF_CEN + (b*C_ + j)*N_ + n];
                sq += d * d;
            }
            const float pd = (sq > 0.f) ? sqrtf(sq) : 0.f;
            psum += fmaxf(2.f * MARGIN_DIST_ - pd, 0.f);
            pcnt += 1.f;
        }
    }
    red[tid] = psum;
    __syncthreads();
    for (int s = TPB/2; s > 0; s >>= 1) {
        if (tid < s) red[tid] += red[tid + s];
        __syncthreads();
    }
    const float tot_push = red[0];
    __syncthreads();
    red[tid] = pcnt;
    __syncthreads();
    for (int s = TPB/2; s > 0; s >>= 1) {
        if (tid < s) red[tid] += red[tid + s];
        __syncthreads();
    }
    if (tid == 0) {
        const float np = red[0];
        out[0] = (np > 0.f) ? tot_push / np : 0.f;   // DIST_WEIGHT = 1
    }
}

// ---------------------------------------------------------------------------
// Kernel 3: pull loss — per-pixel hinge distance to own center
// ---------------------------------------------------------------------------
__global__ __launch_bounds__(TPB) void k_pull(const float* __restrict__ feat,
                                              const int* __restrict__ gt,
                                              const float* __restrict__ ws,
                                              float* __restrict__ out) {
    __shared__ float s_cen[C_][17];   // padded to avoid bank conflicts
    __shared__ float s_w[C_];
    __shared__ float wsum[TPB / 64];

    const int b   = blockIdx.x / BPI;
    const int blk = blockIdx.x % BPI;

    for (int i = threadIdx.x; i < C_*N_; i += TPB)
        s_cen[i / N_][i % N_] = ws[OFF_CEN + b*C_*N_ + i];
    for (int i = threadIdx.x; i < C_; i += TPB)
        s_w[i] = ws[OFF_W + b*C_ + i];
    __syncthreads();

    const float* __restrict__ fb = feat + (size_t)b * N_ * P_;
    const int*   __restrict__ gb = gt   + (size_t)b * P_;

    float acc = 0.f;
    for (int p = blk * TPB + threadIdx.x; p < P_; p += BPI * TPB) {
        const int lab = gb[p];
        if (lab >= 1 && lab <= C_) {
            const int c = lab - 1;
            float sq = 0.f;
            #pragma unroll
            for (int n = 0; n < N_; ++n) {
                const float d = fb[(size_t)n * P_ + p] - s_cen[c][n];
                sq += d * d;
            }
            const float dd = (sq > 0.f) ? sqrtf(sq) : 0.f;
            acc += fmaxf(dd - MARGIN_VAR_, 0.f) * s_w[c];
        }
    }

    // wave reduce (64 lanes), then cross-wave via LDS, one atomic per block
    #pragma unroll
    for (int off = 32; off > 0; off >>= 1) acc += __shfl_down(acc, off, 64);
    const int lane = threadIdx.x & 63, wid = threadIdx.x >> 6;
    if (lane == 0) wsum[wid] = acc;
    __syncthreads();
    if (threadIdx.x == 0) {
        float t = 0.f;
        #pragma unroll
        for (int w = 0; w < TPB/64; ++w) t += wsum[w];
        atomicAdd(out, t);   // VAR_WEIGHT = 1
    }
}

// ---------------------------------------------------------------------------
extern "C" void kernel_launch(void* const* d_in, const int* in_sizes, int n_in,
                              void* d_out, int out_size, void* d_ws, size_t ws_size,
                              hipStream_t stream) {
    const float* feat = (const float*)d_in[0];
    const int*   gt   = (const int*)d_in[1];
    float* out = (float*)d_out;
    float* ws  = (float*)d_ws;

    hipMemsetAsync(d_ws, 0, WS_FLOATS * sizeof(float), stream);

    k_accum<<<dim3(B_ * BPI), dim3(TPB), 0, stream>>>(feat, gt, ws);
    k_centers_push<<<dim3(1), dim3(TPB), 0, stream>>>(ws, out);
    k_pull<<<dim3(B_ * BPI), dim3(TPB), 0, stream>>>(feat, gt, ws, out);
}

// Round 2
// 157.052 us; speedup vs baseline: 1.3695x; 1.3695x over previous
//
#include <hip/hip_runtime.h>

// Problem constants (fixed by reference setup_inputs)
constexpr int B_ = 8;
constexpr int N_ = 16;
constexpr int H_ = 368;
constexpr int W_ = 640;
constexpr int P_ = H_ * W_;          // 235520 pixels per image
constexpr int C_ = 12;               // instance ids 1..12
constexpr float MARGIN_VAR_ = 0.5f;
constexpr float MARGIN_DIST_ = 3.0f;

// Workspace layout (floats)
constexpr int OFF_SUMS = 0;                      // [B][C][N] feature sums
constexpr int OFF_CNT  = OFF_SUMS + B_*C_*N_;    // [B][C]    pixel counts
constexpr int OFF_CEN  = OFF_CNT  + B_*C_;       // [B][C][N] centers
constexpr int OFF_W    = OFF_CEN  + B_*C_*N_;    // [B][C]    pull weights
constexpr int WS_FLOATS = OFF_W + B_*C_;

constexpr int TPB   = 256;             // 4 waves
constexpr int CHUNK = 2048;            // pixels per block
constexpr int BPI   = P_ / CHUNK;      // 115 blocks per image (exact)

__device__ __forceinline__ float wave_reduce(float a) {
    #pragma unroll
    for (int off = 32; off > 0; off >>= 1) a += __shfl_down(a, off, 64);
    return a;
}

// ---------------------------------------------------------------------------
// Kernel 1: per-class feature sums + counts.
// Channel-split: each wave owns channel n = wid*4+nc; lanes accumulate 12
// per-class partial sums in REGISTERS (no LDS atomics), labels staged in LDS.
// ---------------------------------------------------------------------------
__global__ __launch_bounds__(TPB) void k_accum(const float* __restrict__ feat,
                                               const int* __restrict__ gt,
                                               float* __restrict__ ws) {
    __shared__ int4 s_lab4[CHUNK / 4];
    __shared__ float s_red[TPB / 64][C_];
    int* s_lab = (int*)s_lab4;

    const int b     = blockIdx.x / BPI;
    const int chunk = blockIdx.x % BPI;
    const int base  = chunk * CHUNK;
    const int tid   = threadIdx.x;
    const int lane  = tid & 63, wid = tid >> 6;

    const int*   __restrict__ gb = gt   + (size_t)b * P_ + base;
    const float* __restrict__ fb = feat + (size_t)b * N_ * P_ + base;

    // --- stage labels into LDS + count per class in registers ---
    float cnt[C_];
    #pragma unroll
    for (int c = 0; c < C_; ++c) cnt[c] = 0.f;

    #pragma unroll
    for (int k = 0; k < CHUNK / (TPB * 4); ++k) {      // 2 iters
        const int idx = k * (TPB * 4) + tid * 4;
        const int4 lb = *(const int4*)(gb + idx);
        s_lab4[idx / 4] = lb;
        #pragma unroll
        for (int c = 0; c < C_; ++c) {
            cnt[c] += (lb.x == c + 1) ? 1.f : 0.f;
            cnt[c] += (lb.y == c + 1) ? 1.f : 0.f;
            cnt[c] += (lb.z == c + 1) ? 1.f : 0.f;
            cnt[c] += (lb.w == c + 1) ? 1.f : 0.f;
        }
    }
    // block-reduce counts -> global atomics
    #pragma unroll
    for (int c = 0; c < C_; ++c) {
        const float r = wave_reduce(cnt[c]);
        if (lane == 0) s_red[wid][c] = r;
    }
    __syncthreads();
    if (tid < C_) {
        float t = 0.f;
        #pragma unroll
        for (int w = 0; w < TPB / 64; ++w) t += s_red[w][tid];
        atomicAdd(&ws[OFF_CNT + b * C_ + tid], t);
    }

    // --- per-channel register accumulation of class sums ---
    #pragma unroll
    for (int nc = 0; nc < N_ / (TPB / 64); ++nc) {     // 4 channels per wave
        const int n = wid * (N_ / (TPB / 64)) + nc;
        const float* __restrict__ fp = fb + (size_t)n * P_;

        float acc[C_];
        #pragma unroll
        for (int c = 0; c < C_; ++c) acc[c] = 0.f;

        #pragma unroll 2
        for (int i0 = lane * 4; i0 < CHUNK; i0 += 64 * 4) {
            const float4 v  = *(const float4*)(fp + i0);
            const int4   lb = *(const int4*)(s_lab + i0);
            #pragma unroll
            for (int c = 0; c < C_; ++c) {
                acc[c] += (lb.x == c + 1) ? v.x : 0.f;
                acc[c] += (lb.y == c + 1) ? v.y : 0.f;
                acc[c] += (lb.z == c + 1) ? v.z : 0.f;
                acc[c] += (lb.w == c + 1) ? v.w : 0.f;
            }
        }
        #pragma unroll
        for (int c = 0; c < C_; ++c) {
            const float r = wave_reduce(acc[c]);
            if (lane == 0)
                atomicAdd(&ws[OFF_SUMS + ((size_t)b * C_ + c) * N_ + n], r);
        }
    }
}

// ---------------------------------------------------------------------------
// Kernel 2 (1 block): centers, n_inst, pull weights, push loss -> out[0]
// ---------------------------------------------------------------------------
__global__ __launch_bounds__(TPB) void k_centers_push(float* __restrict__ ws,
                                                      float* __restrict__ out) {
    __shared__ float red[TPB];
    __shared__ float s_ninst;
    const int tid = threadIdx.x;

    float pres = 0.f;
    if (tid < B_*C_) pres = (ws[OFF_CNT + tid] > 0.f) ? 1.f : 0.f;
    red[tid] = pres;
    __syncthreads();
    for (int s = TPB/2; s > 0; s >>= 1) {
        if (tid < s) red[tid] += red[tid + s];
        __syncthreads();
    }
    if (tid == 0) s_ninst = red[0];
    __syncthreads();
    const float n_inst = s_ninst;

    for (int i = tid; i < B_*C_*N_; i += TPB) {
        const int bc = i / N_;
        const float cnt = ws[OFF_CNT + bc];
        ws[OFF_CEN + i] = ws[OFF_SUMS + i] / fmaxf(cnt, 1.f);
    }
    for (int i = tid; i < B_*C_; i += TPB) {
        const float cnt = ws[OFF_CNT + i];
        ws[OFF_W + i] = (cnt > 0.f && n_inst > 0.f)
                        ? 1.0f / (fmaxf(cnt, 1.f) * fmaxf(n_inst, 1.f)) : 0.f;
    }
    __syncthreads();

    float psum = 0.f, pcnt = 0.f;
    for (int idx = tid; idx < B_*C_*C_; idx += TPB) {
        const int b   = idx / (C_*C_);
        const int rem = idx % (C_*C_);
        const int i = rem / C_, j = rem % C_;
        if (i == j) continue;
        const float ci = ws[OFF_CNT + b*C_ + i];
        const float cj = ws[OFF_CNT + b*C_ + j];
        if (ci > 0.f && cj > 0.f) {
            float sq = 0.f;
            #pragma unroll
            for (int n = 0; n < N_; ++n) {
                const float d = ws[OFF_CEN + (b*C_ + i)*N_ + n]
                              - ws[OFF_CEN + (b*C_ + j)*N_ + n];
                sq += d * d;
            }
            const float pd = (sq > 0.f) ? sqrtf(sq) : 0.f;
            psum += fmaxf(2.f * MARGIN_DIST_ - pd, 0.f);
            pcnt += 1.f;
        }
    }
    red[tid] = psum;
    __syncthreads();
    for (int s = TPB/2; s > 0; s >>= 1) {
        if (tid < s) red[tid] += red[tid + s];
        __syncthreads();
    }
    const float tot_push = red[0];
    __syncthreads();
    red[tid] = pcnt;
    __syncthreads();
    for (int s = TPB/2; s > 0; s >>= 1) {
        if (tid < s) red[tid] += red[tid + s];
        __syncthreads();
    }
    if (tid == 0) {
        const float np = red[0];
        out[0] = (np > 0.f) ? tot_push / np : 0.f;   // DIST_WEIGHT = 1
    }
}

// ---------------------------------------------------------------------------
// Kernel 3: pull loss — 4 pixels/lane, float4 feature loads, centers in LDS
// ---------------------------------------------------------------------------
__global__ __launch_bounds__(TPB) void k_pull(const float* __restrict__ feat,
                                              const int* __restrict__ gt,
                                              const float* __restrict__ ws,
                                              float* __restrict__ out) {
    __shared__ float s_cen[C_][N_ + 1];   // padded
    __shared__ float s_w[C_ + 1];         // s_w[C_] = 0 for invalid labels
    __shared__ float wsum[TPB / 64];

    const int b     = blockIdx.x / BPI;
    const int chunk = blockIdx.x % BPI;
    const int base  = chunk * CHUNK;
    const int tid   = threadIdx.x;

    for (int i = tid; i < C_*N_; i += TPB)
        s_cen[i / N_][i % N_] = ws[OFF_CEN + b*C_*N_ + i];
    if (tid < C_) s_w[tid] = ws[OFF_W + b*C_ + tid];
    if (tid == C_) s_w[C_] = 0.f;
    __syncthreads();

    const float* __restrict__ fb = feat + (size_t)b * N_ * P_ + base;
    const int*   __restrict__ gb = gt   + (size_t)b * P_ + base;

    float acc = 0.f;
    #pragma unroll
    for (int pass = 0; pass < CHUNK / (TPB * 4); ++pass) {   // 2 passes
        const int p = pass * (TPB * 4) + tid * 4;
        const int4 lb = *(const int4*)(gb + p);
        const bool vx = (lb.x >= 1 && lb.x <= C_);
        const bool vy = (lb.y >= 1 && lb.y <= C_);
        const bool vz = (lb.z >= 1 && lb.z <= C_);
        const bool vw = (lb.w >= 1 && lb.w <= C_);
        const int cx = vx ? lb.x - 1 : 0;
        const int cy = vy ? lb.y - 1 : 0;
        const int cz = vz ? lb.z - 1 : 0;
        const int cw = vw ? lb.w - 1 : 0;

        float sq0 = 0.f, sq1 = 0.f, sq2 = 0.f, sq3 = 0.f;
        #pragma unroll
        for (int n = 0; n < N_; ++n) {
            const float4 v = *(const float4*)(fb + (size_t)n * P_ + p);
            const float d0 = v.x - s_cen[cx][n];
            const float d1 = v.y - s_cen[cy][n];
            const float d2 = v.z - s_cen[cz][n];
            const float d3 = v.w - s_cen[cw][n];
            sq0 += d0 * d0; sq1 += d1 * d1; sq2 += d2 * d2; sq3 += d3 * d3;
        }
        const float w0 = vx ? s_w[cx] : 0.f;
        const float w1 = vy ? s_w[cy] : 0.f;
        const float w2 = vz ? s_w[cz] : 0.f;
        const float w3 = vw ? s_w[cw] : 0.f;
        acc += fmaxf(sqrtf(fmaxf(sq0, 0.f)) - MARGIN_VAR_, 0.f) * w0;
        acc += fmaxf(sqrtf(fmaxf(sq1, 0.f)) - MARGIN_VAR_, 0.f) * w1;
        acc += fmaxf(sqrtf(fmaxf(sq2, 0.f)) - MARGIN_VAR_, 0.f) * w2;
        acc += fmaxf(sqrtf(fmaxf(sq3, 0.f)) - MARGIN_VAR_, 0.f) * w3;
    }

    acc = wave_reduce(acc);
    const int lane = tid & 63, wid = tid >> 6;
    if (lane == 0) wsum[wid] = acc;
    __syncthreads();
    if (tid == 0) {
        float t = 0.f;
        #pragma unroll
        for (int w = 0; w < TPB/64; ++w) t += wsum[w];
        atomicAdd(out, t);   // VAR_WEIGHT = 1
    }
}

// ---------------------------------------------------------------------------
extern "C" void kernel_launch(void* const* d_in, const int* in_sizes, int n_in,
                              void* d_out, int out_size, void* d_ws, size_t ws_size,
                              hipStream_t stream) {
    const float* feat = (const float*)d_in[0];
    const int*   gt   = (const int*)d_in[1];
    float* out = (float*)d_out;
    float* ws  = (float*)d_ws;

    hipMemsetAsync(d_ws, 0, WS_FLOATS * sizeof(float), stream);

    k_accum<<<dim3(B_ * BPI), dim3(TPB), 0, stream>>>(feat, gt, ws);
    k_centers_push<<<dim3(1), dim3(TPB), 0, stream>>>(ws, out);
    k_pull<<<dim3(B_ * BPI), dim3(TPB), 0, stream>>>(feat, gt, ws, out);
}